// Round 5
// baseline (229.093 us; speedup 1.0000x reference)
//
#include <hip/hip_runtime.h>
#include <stdint.h>

#define A_TOTAL 129600   // 9*120*120 anchors per batch
#define NBATCH 8
#define PRE 3000
#define POST 300
#define NWORD 47         // ceil(3000/64)
#define CAP 6144         // candidate buffer per batch
#define NTILE 1128       // 47*48/2 upper-triangle tiles
#define HBLK 32          // wide-scan blocks per batch
#define JCHUNK 768       // ranksort j-chunk (CAP/JCHUNK = 8 chunks)
#define PEND 8           // pipelined full-row loads per window

typedef unsigned long long u64;

__device__ __forceinline__ unsigned xform(float f) {
    unsigned b = __float_as_uint(f);
    return (b & 0x80000000u) ? ~b : (b | 0x80000000u);  // monotonic float->uint
}
__device__ __forceinline__ float unxform(unsigned u) {
    return __uint_as_float((u & 0x80000000u) ? (u & 0x7FFFFFFFu) : ~u);
}
__device__ __forceinline__ u64 readlane64(u64 v, int l) {
    unsigned lo = (unsigned)__builtin_amdgcn_readlane((int)(unsigned)v, l);
    unsigned hi = (unsigned)__builtin_amdgcn_readlane((int)(unsigned)(v >> 32), l);
    return ((u64)hi << 32) | lo;
}

// ---------------- zero histograms + counters + rank array ----------------
__global__ void zero_kernel(unsigned* __restrict__ ghist, int* __restrict__ ccount,
                            int* __restrict__ grank) {
    int g = blockIdx.x * blockDim.x + threadIdx.x;
    if (g < NBATCH * 4096) ghist[g] = 0u;
    else if (g < NBATCH * 4096 + NBATCH) ccount[g - NBATCH * 4096] = 0;
    else if (g < NBATCH * 4096 + NBATCH + NBATCH * CAP)
        grank[g - NBATCH * 4096 - NBATCH] = 0;
}

// ---------------- wide 12-bit histogram (bits 20..31) ----------------
__global__ __launch_bounds__(256) void hist1_kernel(const float* __restrict__ cls,
                                                    unsigned* __restrict__ ghist) {
    const int n = blockIdx.y;
    __shared__ unsigned h[4096];
    for (int i = threadIdx.x; i < 4096; i += 256) h[i] = 0u;
    __syncthreads();
    const float4* c4 = (const float4*)(cls + (size_t)n * A_TOTAL);
    const int n4 = A_TOTAL / 4;   // 32400
    for (int i = blockIdx.x * 256 + threadIdx.x; i < n4; i += HBLK * 256) {
        float4 v = c4[i];
        atomicAdd(&h[xform(v.x) >> 20], 1u);
        atomicAdd(&h[xform(v.y) >> 20], 1u);
        atomicAdd(&h[xform(v.z) >> 20], 1u);
        atomicAdd(&h[xform(v.w) >> 20], 1u);
    }
    __syncthreads();
    unsigned* gh = ghist + n * 4096;
    for (int i = threadIdx.x; i < 4096; i += 256)
        if (h[i]) atomicAdd(&gh[i], h[i]);
}

// ---------------- pick coarse bucket: uT = b<<20 s.t. count(u >= uT) >= PRE ----------------
__global__ __launch_bounds__(256) void pick1_kernel(const unsigned* __restrict__ ghist,
                                                    unsigned* __restrict__ state) {
    const int n = blockIdx.x;
    const int tid = threadIdx.x;
    __shared__ unsigned gsum[256];
    const unsigned* gh = ghist + n * 4096;
    unsigned s = 0;
    for (int q = 0; q < 16; ++q) s += gh[tid * 16 + q];
    gsum[tid] = s;
    __syncthreads();
    if (tid == 0) {
        unsigned acc = 0; int g = 255;
        for (; g > 0; --g) { if (acc + gsum[g] >= PRE) break; acc += gsum[g]; }
        int b = 16 * g + 15;
        for (; b >= 16 * g; --b) { if (acc + gh[b] >= PRE) break; acc += gh[b]; }
        state[n] = ((unsigned)b) << 20;        // coarse threshold
    }
}

// ---------------- wide compaction of all u >= uT (order irrelevant) ----------------
__global__ __launch_bounds__(256) void compact_kernel(const float* __restrict__ cls,
                                                      const unsigned* __restrict__ state,
                                                      u64* __restrict__ cand,
                                                      int* __restrict__ ccount) {
    const int n = blockIdx.y;
    const int tid = threadIdx.x;
    __shared__ u64 lbuf[4096];
    __shared__ unsigned lcnt, lbase;
    if (tid == 0) lcnt = 0u;
    __syncthreads();
    const unsigned uT = state[n];
    const float4* c4 = (const float4*)(cls + (size_t)n * A_TOTAL);
    const int n4 = A_TOTAL / 4;
    for (int i = blockIdx.x * 256 + tid; i < n4; i += HBLK * 256) {
        float4 v = c4[i];
        const float* vf = (const float*)&v;
#pragma unroll
        for (int c = 0; c < 4; ++c) {
            unsigned u = xform(vf[c]);
            if (u >= uT) {
                unsigned slot = atomicAdd(&lcnt, 1u);
                if (slot < 4096u)
                    lbuf[slot] = ((u64)u << 32) | (unsigned)(~(4 * i + c));
            }
        }
    }
    __syncthreads();
    if (tid == 0) lbase = (unsigned)atomicAdd(&ccount[n], (int)min(lcnt, 4096u));
    __syncthreads();
    const unsigned cnt = min(lcnt, 4096u), base = lbase;
    u64* cd = cand + (size_t)n * CAP;
    for (unsigned j = tid; j < cnt; j += 256)
        if (base + j < CAP) cd[base + j] = lbuf[j];
}

// ---------------- partial rank-by-counting: j-dimension split across blocks ----------------
__global__ __launch_bounds__(256) void ranksort_partial(const u64* __restrict__ cand,
                                                        const int* __restrict__ ccount,
                                                        int* __restrict__ grank) {
    const int n = blockIdx.z;
    const int C = min(ccount[n], CAP);
    if (blockIdx.x * 256 >= C) return;
    const int j0 = blockIdx.y * JCHUNK;
    if (j0 >= C) return;
    const int tid = threadIdx.x;
    __shared__ u64 k[JCHUNK];
    const u64* cd = cand + (size_t)n * CAP;
    const int jlim = min(JCHUNK, C - j0);
    for (int j = tid; j < JCHUNK; j += 256)
        k[j] = (j < jlim) ? cd[j0 + j] : 0ull;   // 0 never > any real key
    __syncthreads();
    const int i = blockIdx.x * 256 + tid;
    if (i >= C) return;
    const u64 key = cd[i];
    int rank = 0;
    int j = 0;
    for (; j + 8 <= JCHUNK; j += 8) {
        rank += (k[j] > key) + (k[j+1] > key) + (k[j+2] > key) + (k[j+3] > key)
              + (k[j+4] > key) + (k[j+5] > key) + (k[j+6] > key) + (k[j+7] > key);
    }
    if (rank) atomicAdd(&grank[n * CAP + i], rank);
}

// ---------------- gather: rank -> ordered scores + scrambled box gather ----------------
__global__ __launch_bounds__(256) void rank_gather(const u64* __restrict__ cand,
                                                   const int* __restrict__ ccount,
                                                   const int* __restrict__ grank,
                                                   const float* __restrict__ bbox,
                                                   float* __restrict__ tscores,
                                                   float* __restrict__ boxes) {
    const int n = blockIdx.y;
    const int C = min(ccount[n], CAP);
    const int i = blockIdx.x * 256 + threadIdx.x;
    if (i >= C) return;
    const int rank = grank[n * CAP + i];
    if (rank >= PRE) return;
    const u64 key = cand[(size_t)n * CAP + i];
    const unsigned u = (unsigned)(key >> 32);
    const int r = (int)(~(unsigned)key);     // original flat index
    tscores[n * PRE + rank] = unxform(u);

    // scrambled box gather (replicates reference reshape bug exactly)
    int kp = r % 9;            // k'
    int pp = r / 9;            // h'*120 + w'
    int s_ch = pp % 36;        // source channel
    int qbase = pp / 36;
    int k2 = s_ch >> 2, j2 = s_ch & 3;
    float ratio = (k2 < 3) ? 0.5f : ((k2 < 6) ? 1.0f : 2.0f);
    int si = k2 % 3;
    float scale = (si == 0) ? 8.0f : ((si == 1) ? 16.0f : 32.0f);
    float sq = sqrtf(ratio);
    float wsk = 16.0f * scale / sq;
    float hsk = 16.0f * scale * sq;
    float* outp = boxes + ((size_t)n * PRE + rank) * 4;
#pragma unroll
    for (int j4 = 0; j4 < 4; ++j4) {
        int c = 4 * kp + j4;
        int q = c * 400 + qbase;       // source spatial h*120+w
        int hh = q / 120, w2 = q % 120;
        float cx = (w2 + 0.5f) * 16.0f;
        float cy = (hh + 0.5f) * 16.0f;
        float a;
        if (j2 == 0)      a = cx - 0.5f * wsk;
        else if (j2 == 1) a = cy - 0.5f * hsk;
        else if (j2 == 2) a = cx + 0.5f * wsk;
        else              a = cy + 0.5f * hsk;
        float d = bbox[((size_t)n * 36 + s_ch) * 14400 + q];
        outp[j4] = fminf(fmaxf(a + d, 0.0f), 1919.0f);
    }
}

// ---------------- IoU bitmask, upper-triangle tiles, 4 tiles per block ----------------
__global__ __launch_bounds__(256) void nms_mask_kernel(const float* __restrict__ boxes,
                                                       u64* __restrict__ mask) {
    const int n = blockIdx.y;
    const int t = threadIdx.x & 63;
    const int wv = threadIdx.x >> 6;
    const int T = blockIdx.x * 4 + wv;
    const bool active = (T < NTILE);
    __shared__ float cx1[4][64], cy1[4][64], cx2[4][64], cy2[4][64], car[4][64];
    int rb = 0, cb = 0;
    if (active) {
        int off = 0;
        for (int r = 0; r < NWORD; ++r) {
            int row_tiles = NWORD - r;
            if (T < off + row_tiles) { rb = r; cb = r + (T - off); break; }
            off += row_tiles;
        }
        int cj = cb * 64 + t;
        if (cj < PRE) {
            float4 b4 = *(const float4*)(boxes + ((size_t)n * PRE + cj) * 4);
            cx1[wv][t] = b4.x; cy1[wv][t] = b4.y; cx2[wv][t] = b4.z; cy2[wv][t] = b4.w;
            car[wv][t] = (b4.z - b4.x + 1.0f) * (b4.w - b4.y + 1.0f);
        }
    }
    __syncthreads();
    if (!active) return;
    int i = rb * 64 + t;
    if (i >= PRE) return;
    float4 b4 = *(const float4*)(boxes + ((size_t)n * PRE + i) * 4);
    float x1 = b4.x, y1 = b4.y, x2 = b4.z, y2 = b4.w;
    float ai = (x2 - x1 + 1.0f) * (y2 - y1 + 1.0f);
    u64 w = 0ull;
    int lim = min(64, PRE - cb * 64);
    for (int jj = 0; jj < lim; ++jj) {
        float xx1 = fmaxf(x1, cx1[wv][jj]);
        float yy1 = fmaxf(y1, cy1[wv][jj]);
        float xx2 = fminf(x2, cx2[wv][jj]);
        float yy2 = fminf(y2, cy2[wv][jj]);
        float iw = fmaxf(xx2 - xx1 + 1.0f, 0.0f);
        float ih = fmaxf(yy2 - yy1 + 1.0f, 0.0f);
        float inter = iw * ih;
        float iou = inter / (ai + car[wv][jj] - inter);
        if (iou > 0.5f) w |= (1ull << jj);
    }
    mask[((size_t)n * PRE + i) * NWORD + cb] = w;
}

// ---------------- greedy scan: single-wave, depth-2 software pipeline ----------------
// Per window w: only the diagonal word (in-window suppression), the
// superdiagonal word (carry into window w+1's cur), and full rows of ACCEPTED
// rows (consumed at window w+2 -> ~500cyc load latency hidden behind w+1's scan).
struct PendSet { u64 v[PEND]; int n; };

__device__ __forceinline__ bool scan_window(
    int w, int lane, int lane_cl, const u64* __restrict__ mrow, int* kidx,
    u64& rem, u64& carry, int& cnt,
    u64& diag, u64& sdiag, u64& ndiag, u64& nsdiag, PendSet& pend)
{
    // 1. prefetch next window's diag/sdiag (fire-and-forget)
    if (w + 1 < NWORD) {
        int row = min(64 * (w + 1) + lane, PRE - 1);
        const u64* rp = mrow + (size_t)row * NWORD;
        ndiag = rp[w + 1];
        nsdiag = (w + 2 < NWORD) ? rp[w + 2] : 0ull;
    }
    // 2. consume pend(w-2): loads have had a full window to complete
#pragma unroll
    for (int j = 0; j < PEND; ++j)
        if (j < pend.n) rem |= pend.v[j];
    // 3. scan this window — iterate alive bits only (all values wave-uniform)
    u64 cur = readlane64(rem, w) | carry;
    const int lim = min(64, PRE - 64 * w);
    u64 todo = ~cur;
    if (lim < 64) todo &= (1ull << lim) - 1ull;
    u64 alive = 0ull, carry_next = 0ull;
    while (todo) {
        int b = __ffsll((long long)todo) - 1;
        if (lane == 0) kidx[cnt] = 64 * w + b;
        alive |= 1ull << b;
        cnt++;
        if (cnt >= POST) return true;
        u64 sup = readlane64(diag, b);          // in-window suppression
        carry_next |= readlane64(sdiag, b);     // word w+1 contribution
        todo &= ~(sup | (1ull << b));
    }
    carry = carry_next;
    // 4. issue full-row loads for accepted rows (consumed at w+2)
    u64 aw = alive;
#pragma unroll
    for (int j = 0; j < PEND; ++j) {
        int b = aw ? (__ffsll((long long)aw) - 1) : 0;   // dup row if empty slot
        pend.v[j] = mrow[(size_t)(64 * w + b) * NWORD + lane_cl];
        aw &= aw - 1;
    }
    pend.n = min(__popcll(alive), PEND);
    // rare overflow (>PEND accepts in one window): blocking update
    while (aw) {
        int b = __ffsll((long long)aw) - 1; aw &= aw - 1;
        rem |= mrow[(size_t)(64 * w + b) * NWORD + lane_cl];
    }
    return false;
}

__global__ __launch_bounds__(64) void nms_scan_kernel(const u64* __restrict__ mask,
                                                      const float* __restrict__ tscores,
                                                      const float* __restrict__ boxes,
                                                      float* __restrict__ kept_scores,
                                                      float* __restrict__ out) {
    const int n = blockIdx.x;
    const int lane = threadIdx.x;
    const int lane_cl = min(lane, NWORD - 1);
    __shared__ int kidx[POST];
    const u64* mrow = mask + (size_t)n * PRE * NWORD;

    u64 diagA, sdiagA, diagB = 0, sdiagB = 0;
    {   // preload window 0
        const u64* rp = mrow + (size_t)lane * NWORD;
        diagA = rp[0]; sdiagA = rp[1];
    }
    PendSet pA, pB; pA.n = 0; pB.n = 0;
    u64 rem = 0ull, carry = 0ull;
    int cnt = 0;
    for (int w = 0; w < NWORD; ++w) {
        bool full;
        if ((w & 1) == 0)
            full = scan_window(w, lane, lane_cl, mrow, kidx, rem, carry, cnt,
                               diagA, sdiagA, diagB, sdiagB, pA);
        else
            full = scan_window(w, lane, lane_cl, mrow, kidx, rem, carry, cnt,
                               diagB, sdiagB, diagA, sdiagA, pB);
        if (full) break;
    }
    __syncthreads();
    for (int t = lane; t < POST; t += 64) {
        float* op = out + ((size_t)n * POST + t) * 5;
        if (t < cnt) {
            int i = kidx[t];
            kept_scores[n * POST + t] = tscores[n * PRE + i];
            const float* bp = boxes + ((size_t)n * PRE + i) * 4;
            op[1] = bp[0]; op[2] = bp[1]; op[3] = bp[2]; op[4] = bp[3];
        } else {
            kept_scores[n * POST + t] = 0.0f;
            op[1] = 0.0f; op[2] = 0.0f; op[3] = 0.0f; op[4] = 0.0f;
        }
    }
}

// ---------------- score column: batch 7's kept scores broadcast ----------------
__global__ void scorecol_kernel(const float* __restrict__ kept_scores,
                                float* __restrict__ out) {
    int g = blockIdx.x * blockDim.x + threadIdx.x;
    if (g >= NBATCH * POST) return;
    int t = g % POST;
    out[(size_t)g * 5] = kept_scores[(NBATCH - 1) * POST + t];
}

extern "C" void kernel_launch(void* const* d_in, const int* in_sizes, int n_in,
                              void* d_out, int out_size, void* d_ws, size_t ws_size,
                              hipStream_t stream) {
    const float* cls = (const float*)d_in[0];   // (8,9,120,120)
    const float* bbox = (const float*)d_in[1];  // (8,36,120,120)
    float* out = (float*)d_out;                 // (8,300,5)

    char* p = (char*)d_ws;
    // Overlay: ghist/state/ccount/cand/grank are dead before mask is written (stream order).
    u64* mask = (u64*)p;                               // 8*3000*47*8 = 9,024,000
    unsigned* ghist = (unsigned*)p;                    // 131,072
    unsigned* state = (unsigned*)(p + 131072);         // 32
    int* ccount = (int*)(p + 131200);                  // 32
    u64* cand = (u64*)(p + 131584);                    // 8*6144*8 = 393,216 (ends 524,800)
    int* grank = (int*)(p + 524800);                   // 8*6144*4 = 196,608 (ends 721,408)
    float* tscores = (float*)(p + 9024000);            // 96,000
    float* boxes = (float*)(p + 9120000);              // 384,000
    float* kept_scores = (float*)(p + 9504000);        // 9,600  (total 9,513,600)
    (void)ws_size; (void)n_in; (void)in_sizes; (void)out_size;

    zero_kernel<<<(NBATCH * 4096 + NBATCH + NBATCH * CAP + 255) / 256, 256, 0, stream>>>(ghist, ccount, grank);
    hist1_kernel<<<dim3(HBLK, NBATCH), 256, 0, stream>>>(cls, ghist);
    pick1_kernel<<<NBATCH, 256, 0, stream>>>(ghist, state);
    compact_kernel<<<dim3(HBLK, NBATCH), 256, 0, stream>>>(cls, state, cand, ccount);
    ranksort_partial<<<dim3(CAP / 256, CAP / JCHUNK, NBATCH), 256, 0, stream>>>(cand, ccount, grank);
    rank_gather<<<dim3(CAP / 256, NBATCH), 256, 0, stream>>>(cand, ccount, grank, bbox, tscores, boxes);
    nms_mask_kernel<<<dim3((NTILE + 3) / 4, NBATCH), 256, 0, stream>>>(boxes, mask);
    nms_scan_kernel<<<NBATCH, 64, 0, stream>>>(mask, tscores, boxes, kept_scores, out);
    scorecol_kernel<<<(NBATCH * POST + 255) / 256, 256, 0, stream>>>(kept_scores, out);
}

// Round 6
// 182.348 us; speedup vs baseline: 1.2564x; 1.2564x over previous
//
#include <hip/hip_runtime.h>
#include <stdint.h>

#define A_TOTAL 129600   // 9*120*120 anchors per batch
#define NBATCH 8
#define PRE 3000
#define POST 300
#define NWORD 47         // ceil(3000/64)
#define CAP 6144         // candidate buffer per batch
#define NTILE 1128       // 47*48/2 upper-triangle tiles
#define HBLK 32          // wide-scan blocks per batch
#define JCHUNK 768       // ranksort j-chunk (CAP/JCHUNK = 8 chunks)

typedef unsigned long long u64;

__device__ __forceinline__ unsigned xform(float f) {
    unsigned b = __float_as_uint(f);
    return (b & 0x80000000u) ? ~b : (b | 0x80000000u);  // monotonic float->uint
}
__device__ __forceinline__ float unxform(unsigned u) {
    return __uint_as_float((u & 0x80000000u) ? (u & 0x7FFFFFFFu) : ~u);
}
__device__ __forceinline__ u64 readlane64(u64 v, int l) {
    unsigned lo = (unsigned)__builtin_amdgcn_readlane((int)(unsigned)v, l);
    unsigned hi = (unsigned)__builtin_amdgcn_readlane((int)(unsigned)(v >> 32), l);
    return ((u64)hi << 32) | lo;
}

// ---------------- zero histograms + counters + rank array ----------------
__global__ void zero_kernel(unsigned* __restrict__ ghist, int* __restrict__ ccount,
                            int* __restrict__ grank) {
    int g = blockIdx.x * blockDim.x + threadIdx.x;
    if (g < NBATCH * 4096) ghist[g] = 0u;
    else if (g < NBATCH * 4096 + NBATCH) ccount[g - NBATCH * 4096] = 0;
    else if (g < NBATCH * 4096 + NBATCH + NBATCH * CAP)
        grank[g - NBATCH * 4096 - NBATCH] = 0;
}

// ---------------- wide 12-bit histogram (bits 20..31) ----------------
__global__ __launch_bounds__(256) void hist1_kernel(const float* __restrict__ cls,
                                                    unsigned* __restrict__ ghist) {
    const int n = blockIdx.y;
    __shared__ unsigned h[4096];
    for (int i = threadIdx.x; i < 4096; i += 256) h[i] = 0u;
    __syncthreads();
    const float4* c4 = (const float4*)(cls + (size_t)n * A_TOTAL);
    const int n4 = A_TOTAL / 4;   // 32400
    for (int i = blockIdx.x * 256 + threadIdx.x; i < n4; i += HBLK * 256) {
        float4 v = c4[i];
        atomicAdd(&h[xform(v.x) >> 20], 1u);
        atomicAdd(&h[xform(v.y) >> 20], 1u);
        atomicAdd(&h[xform(v.z) >> 20], 1u);
        atomicAdd(&h[xform(v.w) >> 20], 1u);
    }
    __syncthreads();
    unsigned* gh = ghist + n * 4096;
    for (int i = threadIdx.x; i < 4096; i += 256)
        if (h[i]) atomicAdd(&gh[i], h[i]);
}

// ---------------- pick coarse bucket: uT = b<<20 s.t. count(u >= uT) >= PRE ----------------
__global__ __launch_bounds__(256) void pick1_kernel(const unsigned* __restrict__ ghist,
                                                    unsigned* __restrict__ state) {
    const int n = blockIdx.x;
    const int tid = threadIdx.x;
    __shared__ unsigned gsum[256];
    const unsigned* gh = ghist + n * 4096;
    unsigned s = 0;
    for (int q = 0; q < 16; ++q) s += gh[tid * 16 + q];
    gsum[tid] = s;
    __syncthreads();
    if (tid == 0) {
        unsigned acc = 0; int g = 255;
        for (; g > 0; --g) { if (acc + gsum[g] >= PRE) break; acc += gsum[g]; }
        int b = 16 * g + 15;
        for (; b >= 16 * g; --b) { if (acc + gh[b] >= PRE) break; acc += gh[b]; }
        state[n] = ((unsigned)b) << 20;        // coarse threshold
    }
}

// ---------------- wide compaction of all u >= uT (order irrelevant) ----------------
__global__ __launch_bounds__(256) void compact_kernel(const float* __restrict__ cls,
                                                      const unsigned* __restrict__ state,
                                                      u64* __restrict__ cand,
                                                      int* __restrict__ ccount) {
    const int n = blockIdx.y;
    const int tid = threadIdx.x;
    __shared__ u64 lbuf[4096];
    __shared__ unsigned lcnt, lbase;
    if (tid == 0) lcnt = 0u;
    __syncthreads();
    const unsigned uT = state[n];
    const float4* c4 = (const float4*)(cls + (size_t)n * A_TOTAL);
    const int n4 = A_TOTAL / 4;
    for (int i = blockIdx.x * 256 + tid; i < n4; i += HBLK * 256) {
        float4 v = c4[i];
        const float* vf = (const float*)&v;
#pragma unroll
        for (int c = 0; c < 4; ++c) {
            unsigned u = xform(vf[c]);
            if (u >= uT) {
                unsigned slot = atomicAdd(&lcnt, 1u);
                if (slot < 4096u)
                    lbuf[slot] = ((u64)u << 32) | (unsigned)(~(4 * i + c));
            }
        }
    }
    __syncthreads();
    if (tid == 0) lbase = (unsigned)atomicAdd(&ccount[n], (int)min(lcnt, 4096u));
    __syncthreads();
    const unsigned cnt = min(lcnt, 4096u), base = lbase;
    u64* cd = cand + (size_t)n * CAP;
    for (unsigned j = tid; j < cnt; j += 256)
        if (base + j < CAP) cd[base + j] = lbuf[j];
}

// ---------------- partial rank-by-counting: j-dimension split across blocks ----------------
__global__ __launch_bounds__(256) void ranksort_partial(const u64* __restrict__ cand,
                                                        const int* __restrict__ ccount,
                                                        int* __restrict__ grank) {
    const int n = blockIdx.z;
    const int C = min(ccount[n], CAP);
    if (blockIdx.x * 256 >= C) return;
    const int j0 = blockIdx.y * JCHUNK;
    if (j0 >= C) return;
    const int tid = threadIdx.x;
    __shared__ u64 k[JCHUNK];
    const u64* cd = cand + (size_t)n * CAP;
    const int jlim = min(JCHUNK, C - j0);
    for (int j = tid; j < JCHUNK; j += 256)
        k[j] = (j < jlim) ? cd[j0 + j] : 0ull;   // 0 never > any real key
    __syncthreads();
    const int i = blockIdx.x * 256 + tid;
    if (i >= C) return;
    const u64 key = cd[i];
    int rank = 0;
    int j = 0;
    for (; j + 8 <= JCHUNK; j += 8) {
        rank += (k[j] > key) + (k[j+1] > key) + (k[j+2] > key) + (k[j+3] > key)
              + (k[j+4] > key) + (k[j+5] > key) + (k[j+6] > key) + (k[j+7] > key);
    }
    if (rank) atomicAdd(&grank[n * CAP + i], rank);
}

// ---------------- gather: rank -> ordered scores + scrambled box gather ----------------
__global__ __launch_bounds__(256) void rank_gather(const u64* __restrict__ cand,
                                                   const int* __restrict__ ccount,
                                                   const int* __restrict__ grank,
                                                   const float* __restrict__ bbox,
                                                   float* __restrict__ tscores,
                                                   float* __restrict__ boxes) {
    const int n = blockIdx.y;
    const int C = min(ccount[n], CAP);
    const int i = blockIdx.x * 256 + threadIdx.x;
    if (i >= C) return;
    const int rank = grank[n * CAP + i];
    if (rank >= PRE) return;
    const u64 key = cand[(size_t)n * CAP + i];
    const unsigned u = (unsigned)(key >> 32);
    const int r = (int)(~(unsigned)key);     // original flat index
    tscores[n * PRE + rank] = unxform(u);

    // scrambled box gather (replicates reference reshape bug exactly)
    int kp = r % 9;            // k'
    int pp = r / 9;            // h'*120 + w'
    int s_ch = pp % 36;        // source channel
    int qbase = pp / 36;
    int k2 = s_ch >> 2, j2 = s_ch & 3;
    float ratio = (k2 < 3) ? 0.5f : ((k2 < 6) ? 1.0f : 2.0f);
    int si = k2 % 3;
    float scale = (si == 0) ? 8.0f : ((si == 1) ? 16.0f : 32.0f);
    float sq = sqrtf(ratio);
    float wsk = 16.0f * scale / sq;
    float hsk = 16.0f * scale * sq;
    float* outp = boxes + ((size_t)n * PRE + rank) * 4;
#pragma unroll
    for (int j4 = 0; j4 < 4; ++j4) {
        int c = 4 * kp + j4;
        int q = c * 400 + qbase;       // source spatial h*120+w
        int hh = q / 120, w2 = q % 120;
        float cx = (w2 + 0.5f) * 16.0f;
        float cy = (hh + 0.5f) * 16.0f;
        float a;
        if (j2 == 0)      a = cx - 0.5f * wsk;
        else if (j2 == 1) a = cy - 0.5f * hsk;
        else if (j2 == 2) a = cx + 0.5f * wsk;
        else              a = cy + 0.5f * hsk;
        float d = bbox[((size_t)n * 36 + s_ch) * 14400 + q];
        outp[j4] = fminf(fmaxf(a + d, 0.0f), 1919.0f);
    }
}

// ---------------- IoU bitmask, upper-triangle tiles, 4 tiles per block ----------------
__global__ __launch_bounds__(256) void nms_mask_kernel(const float* __restrict__ boxes,
                                                       u64* __restrict__ mask) {
    const int n = blockIdx.y;
    const int t = threadIdx.x & 63;
    const int wv = threadIdx.x >> 6;
    const int T = blockIdx.x * 4 + wv;
    const bool active = (T < NTILE);
    __shared__ float cx1[4][64], cy1[4][64], cx2[4][64], cy2[4][64], car[4][64];
    int rb = 0, cb = 0;
    if (active) {
        int off = 0;
        for (int r = 0; r < NWORD; ++r) {
            int row_tiles = NWORD - r;
            if (T < off + row_tiles) { rb = r; cb = r + (T - off); break; }
            off += row_tiles;
        }
        int cj = cb * 64 + t;
        if (cj < PRE) {
            float4 b4 = *(const float4*)(boxes + ((size_t)n * PRE + cj) * 4);
            cx1[wv][t] = b4.x; cy1[wv][t] = b4.y; cx2[wv][t] = b4.z; cy2[wv][t] = b4.w;
            car[wv][t] = (b4.z - b4.x + 1.0f) * (b4.w - b4.y + 1.0f);
        }
    }
    __syncthreads();
    if (!active) return;
    int i = rb * 64 + t;
    if (i >= PRE) return;
    float4 b4 = *(const float4*)(boxes + ((size_t)n * PRE + i) * 4);
    float x1 = b4.x, y1 = b4.y, x2 = b4.z, y2 = b4.w;
    float ai = (x2 - x1 + 1.0f) * (y2 - y1 + 1.0f);
    u64 w = 0ull;
    int lim = min(64, PRE - cb * 64);
    for (int jj = 0; jj < lim; ++jj) {
        float xx1 = fmaxf(x1, cx1[wv][jj]);
        float yy1 = fmaxf(y1, cy1[wv][jj]);
        float xx2 = fminf(x2, cx2[wv][jj]);
        float yy2 = fminf(y2, cy2[wv][jj]);
        float iw = fmaxf(xx2 - xx1 + 1.0f, 0.0f);
        float ih = fmaxf(yy2 - yy1 + 1.0f, 0.0f);
        float inter = iw * ih;
        float iou = inter / (ai + car[wv][jj] - inter);
        if (iou > 0.5f) w |= (1ull << jj);
    }
    mask[((size_t)n * PRE + i) * NWORD + cb] = w;
}

// ---------------- greedy scan: LDS window tiles, double-buffered prefetch,
// alive-only inner loop. Wave 0 scans window w from LDS while waves 1..3
// prefetch window w+1 (coalesced). Block 7 also writes output column 0
// (reference broadcasts batch 7's scores to all batches).
#define TSTRIDE 49   // u64 stride: breaks bank aliasing on column reads
__global__ __launch_bounds__(256) void nms_scan_kernel(const u64* __restrict__ mask,
                                                       const float* __restrict__ tscores,
                                                       const float* __restrict__ boxes,
                                                       float* __restrict__ out) {
    const int n = blockIdx.x;
    const int tid = threadIdx.x;
    const int lane = tid & 63;
    const int wv = tid >> 6;
    __shared__ u64 tile[2][64 * TSTRIDE];   // 2 * 24.5 KB
    __shared__ int kidx[POST];
    __shared__ int s_cnt;
    const u64* mrow = mask + (size_t)n * PRE * NWORD;

    // prefetch window 0 (all threads)
    for (int idx = tid; idx < 64 * NWORD; idx += 256) {
        int r = idx / NWORD, wd = idx % NWORD;
        tile[0][r * TSTRIDE + wd] = mrow[(size_t)r * NWORD + wd];  // rows 0..63 < PRE
    }
    if (tid == 0) s_cnt = 0;
    __syncthreads();

    u64 rem = 0ull;   // wave 0: lane l holds suppression word l
    for (int w = 0; w < NWORD; ++w) {
        const int buf = w & 1;
        if (wv > 0 && w + 1 < NWORD) {           // prefetch next window
            const int base = 64 * (w + 1);
            for (int idx = tid - 64; idx < 64 * NWORD; idx += 192) {
                int r = idx / NWORD, wd = idx % NWORD;
                int row = base + r;
                tile[buf ^ 1][r * TSTRIDE + wd] =
                    (row < PRE) ? mrow[(size_t)row * NWORD + wd] : 0ull;
            }
        }
        if (wv == 0) {
            int cnt = s_cnt;                      // uniform
            const int base = 64 * w;
            const int lim = min(64, PRE - base);
            u64 vrow = (lane < lim) ? tile[buf][lane * TSTRIDE + w] : 0ull;
            u64 cur = readlane64(rem, w);
            u64 todo = ~cur;
            if (lim < 64) todo &= (1ull << lim) - 1ull;
            u64 alive = 0ull;
            while (todo) {                        // iterate ALIVE bits only
                int b = __ffsll((long long)todo) - 1;
                if (lane == 0) kidx[cnt] = base + b;
                alive |= 1ull << b;
                cnt++;
                if (cnt >= POST) break;
                u64 sup = readlane64(vrow, b);    // in-window suppression
                todo &= ~(sup | (1ull << b));
            }
            // cross-window rem updates from LDS, 4 outstanding reads
            if (lane < NWORD) {
                u64 t2 = alive;
                while (t2) {
                    int b0 = __ffsll((long long)t2) - 1; t2 &= t2 - 1;
                    int b1 = b0, b2 = b0, b3 = b0;
                    if (t2) { b1 = __ffsll((long long)t2) - 1; t2 &= t2 - 1; }
                    if (t2) { b2 = __ffsll((long long)t2) - 1; t2 &= t2 - 1; }
                    if (t2) { b3 = __ffsll((long long)t2) - 1; t2 &= t2 - 1; }
                    u64 a0 = tile[buf][b0 * TSTRIDE + lane];
                    u64 a1 = tile[buf][b1 * TSTRIDE + lane];
                    u64 a2 = tile[buf][b2 * TSTRIDE + lane];
                    u64 a3 = tile[buf][b3 * TSTRIDE + lane];
                    rem |= (a0 | a1) | (a2 | a3);
                }
            }
            if (lane == 0) s_cnt = cnt;
        }
        __syncthreads();
        if (s_cnt >= POST) break;
    }

    const int cnt = s_cnt;
    for (int t = tid; t < POST; t += 256) {
        float* op = out + ((size_t)n * POST + t) * 5;
        if (t < cnt) {
            int i = kidx[t];
            const float* bp = boxes + ((size_t)n * PRE + i) * 4;
            op[1] = bp[0]; op[2] = bp[1]; op[3] = bp[2]; op[4] = bp[3];
        } else {
            op[1] = 0.0f; op[2] = 0.0f; op[3] = 0.0f; op[4] = 0.0f;
        }
        if (n == NBATCH - 1) {
            // reference: score column = batch 7's kept scores, broadcast to all
            float sv = (t < cnt) ? tscores[n * PRE + kidx[t]] : 0.0f;
            for (int m = 0; m < NBATCH; ++m)
                out[((size_t)m * POST + t) * 5] = sv;
        }
    }
}

extern "C" void kernel_launch(void* const* d_in, const int* in_sizes, int n_in,
                              void* d_out, int out_size, void* d_ws, size_t ws_size,
                              hipStream_t stream) {
    const float* cls = (const float*)d_in[0];   // (8,9,120,120)
    const float* bbox = (const float*)d_in[1];  // (8,36,120,120)
    float* out = (float*)d_out;                 // (8,300,5)

    char* p = (char*)d_ws;
    // Overlay: ghist/state/ccount/cand/grank are dead before mask is written (stream order).
    u64* mask = (u64*)p;                               // 8*3000*47*8 = 9,024,000
    unsigned* ghist = (unsigned*)p;                    // 131,072
    unsigned* state = (unsigned*)(p + 131072);         // 32
    int* ccount = (int*)(p + 131200);                  // 32
    u64* cand = (u64*)(p + 131584);                    // 8*6144*8 = 393,216 (ends 524,800)
    int* grank = (int*)(p + 524800);                   // 8*6144*4 = 196,608 (ends 721,408)
    float* tscores = (float*)(p + 9024000);            // 96,000
    float* boxes = (float*)(p + 9120000);              // 384,000 (total 9,504,000)
    (void)ws_size; (void)n_in; (void)in_sizes; (void)out_size;

    zero_kernel<<<(NBATCH * 4096 + NBATCH + NBATCH * CAP + 255) / 256, 256, 0, stream>>>(ghist, ccount, grank);
    hist1_kernel<<<dim3(HBLK, NBATCH), 256, 0, stream>>>(cls, ghist);
    pick1_kernel<<<NBATCH, 256, 0, stream>>>(ghist, state);
    compact_kernel<<<dim3(HBLK, NBATCH), 256, 0, stream>>>(cls, state, cand, ccount);
    ranksort_partial<<<dim3(CAP / 256, CAP / JCHUNK, NBATCH), 256, 0, stream>>>(cand, ccount, grank);
    rank_gather<<<dim3(CAP / 256, NBATCH), 256, 0, stream>>>(cand, ccount, grank, bbox, tscores, boxes);
    nms_mask_kernel<<<dim3((NTILE + 3) / 4, NBATCH), 256, 0, stream>>>(boxes, mask);
    nms_scan_kernel<<<NBATCH, 256, 0, stream>>>(mask, tscores, boxes, out);
}